// Round 6
// baseline (307.708 us; speedup 1.0000x reference)
//
#include <hip/hip_runtime.h>
#include <hip/hip_bf16.h>
#include <cstdint>
#include <cstddef>

#define B_  4
#define T_  2048
#define C_  1024
#define H_  16
#define D_  64
#define MROWS (B_*T_)      // 8192
#define NDIM  (H_*D_)      // 1024

typedef float  f32x4 __attribute__((ext_vector_type(4)));
typedef __bf16 bfrag __attribute__((ext_vector_type(8)));

__device__ __forceinline__ unsigned short f2bf(float f) {
  union { float f; unsigned u; } v; v.f = f;
  unsigned r = v.u + 0x7fffu + ((v.u >> 16) & 1u);
  return (unsigned short)(r >> 16);
}

__device__ __forceinline__ void async_load16(const void* g, void* l) {
  __builtin_amdgcn_global_load_lds((__attribute__((address_space(1))) void*)(void*)g,
                                   (__attribute__((address_space(3))) void*)l,
                                   16, 0, 0);
}

// pack two f32 -> 2xbf16 (RNE) in one VALU op; low16 = cvt(f0)
__device__ __forceinline__ unsigned cvt_pk_bf16(float f0, float f1) {
  unsigned r;
  asm("v_cvt_pk_bf16_f32 %0, %1, %2" : "=v"(r) : "v"(f0), "v"(f1));
  return r;
}

// ---------------- fused prep: cvt q/k/v -> bf16, transpose Wq/Wk/Wv, Wo ----
// Grid 4096 (was 25600 — tiny blocks were dispatch-rate-bound, not BW-bound):
//   [0,3072): cvt, grid-strided 8 x float4 per thread (8192 f32 per block).
//   [3072,3840): wqkv transpose.  [3840,4096): wo transpose.
__global__ __launch_bounds__(256) void prep_kernel(
    const float* __restrict__ q, const float* __restrict__ k, const float* __restrict__ v,
    unsigned short* __restrict__ qb, unsigned short* __restrict__ kb, unsigned short* __restrict__ vb,
    const float* __restrict__ Wq, const float* __restrict__ Wk, const float* __restrict__ Wv,
    unsigned short* __restrict__ wqT, unsigned short* __restrict__ wkT, unsigned short* __restrict__ wvT,
    const float* __restrict__ Wo, unsigned short* __restrict__ woT)
{
  const int id = blockIdx.x, tid = threadIdx.x;
  if (id < 3072) {
    int z = id >> 10, blk = id & 1023;          // 1024 blocks per tensor
    const float* in = z == 0 ? q : z == 1 ? k : v;
    unsigned short* out = z == 0 ? qb : z == 1 ? kb : vb;
    int base = blk * 2048;                      // in float4 units; 2048 f4/block
#pragma unroll
    for (int r2 = 0; r2 < 8; ++r2) {
      int i = (base + r2 * 256 + tid) * 4;
      float4 vv = *(const float4*)(in + i);
      ushort4 rr;
      rr.x = f2bf(vv.x); rr.y = f2bf(vv.y); rr.z = f2bf(vv.z); rr.w = f2bf(vv.w);
      *(ushort4*)(out + i) = rr;
    }
  } else if (id < 3840) {
    int u = id - 3072;
    int z = u >> 4, cblk = u & 15;
    int sel = z >> 4, h = z & 15;
    const float* in = (sel == 0 ? Wq : sel == 1 ? Wk : Wv) + (size_t)h * C_ * D_; // [C][D]
    unsigned short* out = (sel == 0 ? wqT : sel == 1 ? wkT : wvT) + (size_t)h * D_ * C_; // [D][C]
    __shared__ float tile[64][65];
    int c0 = cblk * 64;
    int x = tid & 63, y4 = tid >> 6;
    for (int r = y4; r < 64; r += 4)
      tile[r][x] = in[(size_t)(c0 + r) * D_ + x];
    __syncthreads();
    for (int r = y4; r < 64; r += 4)
      out[(size_t)r * C_ + c0 + x] = f2bf(tile[x][r]);
  } else {
    int u = id - 3840;
    __shared__ float tile[64][65];
    int i0 = (u >> 4) * 64, j0 = (u & 15) * 64;
    int x = tid & 63, y4 = tid >> 6;
    for (int r = y4; r < 64; r += 4)
      tile[r][x] = Wo[(size_t)(i0 + r) * C_ + j0 + x];
    __syncthreads();
    for (int r = y4; r < 64; r += 4)
      woT[(size_t)(j0 + r) * NDIM + i0 + x] = f2bf(tile[x][r]);
  }
}

// ---------------- QKV GEMM: C[M,N] = A[M,K] * Bt[N,K]^T (bf16, fp32 acc) ---
// R5-proven: 256x128 tile, BK=64, 512 threads (8 waves, 4Mx2N of 64x64),
// 48 KiB LDS, VGPR~60 -> 3 blocks/CU all-co-resident (768 blocks).
// z==0 -> bf16 out PRE-SCALED by log2(e)/32 (flash softmax folds it);
// z==1 -> bf16 row-major; z==2 -> V-transposed bf16 out
//   element (m=b*2048+t, n=h*64+d) -> out[((b*16+h)*64+d)*T_ + t].
__global__ __launch_bounds__(512, 4) void gemm_qkv(
    const unsigned short* __restrict__ A0, const unsigned short* __restrict__ A1, const unsigned short* __restrict__ A2,
    const unsigned short* __restrict__ B0, const unsigned short* __restrict__ B1, const unsigned short* __restrict__ B2,
    void* C0, void* C1, void* C2)
{
  constexpr int K = C_;     // 1024
  constexpr int N = NDIM;   // 1024
  __shared__ __align__(16) short As[256 * 64];   // 32 KiB
  __shared__ __align__(16) short Bs[128 * 64];   // 16 KiB

  const int id = blockIdx.x;
  const int xcd = id & 7, s = id >> 3;
  const int z = s >> 5;
  const int t = s & 31;
  const int mb = xcd * 4 + (t >> 3);   // 32 m-blocks of 256 rows
  const int nb = t & 7;                // 8 n-blocks of 128 cols

  const unsigned short* A  = z == 0 ? A0 : z == 1 ? A1 : A2;
  const unsigned short* Bt = z == 0 ? B0 : z == 1 ? B1 : B2;
  void* Cv                 = z == 0 ? C0 : z == 1 ? C1 : C2;

  const int tid = threadIdx.x, lane = tid & 63, wave = tid >> 6;
  const int quad = lane >> 4, l15 = lane & 15;
  const int m0 = mb * 256, n0 = nb * 128;
  const int wm = (wave >> 1) * 64, wn = (wave & 1) * 64;
  const int wbase = tid & ~63;         // wave-uniform LDS chunk base

  f32x4 acc[4][4] = {};

  for (int k0 = 0; k0 < K; k0 += 64) {
#pragma unroll
    for (int i = 0; i < 4; ++i) {
      int p0 = i * 512 + wbase;
      int p = p0 + lane;
      int m = p >> 3, cl = (p & 7) ^ (m & 7);
      async_load16(A + (size_t)(m0 + m) * K + k0 + cl * 8, (char*)As + p0 * 16);
    }
#pragma unroll
    for (int i = 0; i < 2; ++i) {
      int p0 = i * 512 + wbase;
      int p = p0 + lane;
      int m = p >> 3, cl = (p & 7) ^ (m & 7);
      async_load16(Bt + (size_t)(n0 + m) * K + k0 + cl * 8, (char*)Bs + p0 * 16);
    }
    __syncthreads();
#pragma unroll
    for (int ks = 0; ks < 2; ++ks) {
      bfrag af[4], bf[4];
#pragma unroll
      for (int i = 0; i < 4; ++i) {
        int m = wm + i * 16 + l15;
        int c = (ks * 4 + quad) ^ (m & 7);
        af[i] = *(const bfrag*)(As + m * 64 + c * 8);
        int n = wn + i * 16 + l15;
        int c2 = (ks * 4 + quad) ^ (n & 7);
        bf[i] = *(const bfrag*)(Bs + n * 64 + c2 * 8);
      }
#pragma unroll
      for (int i = 0; i < 4; ++i)
#pragma unroll
        for (int j = 0; j < 4; ++j)
          acc[i][j] = __builtin_amdgcn_mfma_f32_16x16x32_bf16(af[i], bf[j], acc[i][j], 0, 0, 0);
    }
    __syncthreads();
  }

  if (z < 2) {
    const float sc = (z == 0) ? 0.045084220f : 1.0f;   // log2(e)/32 folded into Q
    unsigned short* Cb = (unsigned short*)Cv;
#pragma unroll
    for (int i = 0; i < 4; ++i) {
      int row0 = m0 + wm + i * 16 + quad * 4;
#pragma unroll
      for (int j = 0; j < 4; ++j) {
        int col = n0 + wn + j * 16 + l15;
#pragma unroll
        for (int r = 0; r < 4; ++r)
          Cb[(size_t)(row0 + r) * N + col] = f2bf(acc[i][j][r] * sc);
      }
    }
  } else {
    unsigned short* Vo = (unsigned short*)Cv;
#pragma unroll
    for (int i = 0; i < 4; ++i) {
      int m = m0 + wm + i * 16 + quad * 4;      // token index, 4 consecutive
      int bb = m >> 11, tt = m & 2047;
#pragma unroll
      for (int j = 0; j < 4; ++j) {
        int n = n0 + wn + j * 16 + l15;
        int hh = n >> 6, dd = n & 63;
        ushort4 pk;
        pk.x = f2bf(acc[i][j][0]); pk.y = f2bf(acc[i][j][1]);
        pk.z = f2bf(acc[i][j][2]); pk.w = f2bf(acc[i][j][3]);
        *(ushort4*)(Vo + (((size_t)bb * 16 + hh) * 64 + dd) * T_ + tt) = pk;
      }
    }
  }
}

// ---------------- output projection: 128x128 tile, 256 thr, 512 blocks -----
// R0-proven shape. 32 KiB LDS, VGPR~84 -> 2 blocks/CU co-resident (512/256),
// restoring the inter-block overlap the 256-block/1-per-CU variant lacked.
// out = attO[8192,1024] x woT^T + bias (fp32 out).
__global__ __launch_bounds__(256) void gemm_o(
    const unsigned short* __restrict__ A, const unsigned short* __restrict__ Bt,
    float* __restrict__ Cf, const float* __restrict__ bias)
{
  constexpr int K = NDIM;   // 1024
  constexpr int N = C_;     // 1024
  __shared__ __align__(16) short As[128 * 64];
  __shared__ __align__(16) short Bs[128 * 64];

  const int id = blockIdx.x;
  const int xcd = id & 7, t = id >> 3;         // t in [0,64)
  const int mb = xcd * 8 + (t >> 3);           // 64 m-blocks of 128 rows
  const int nb = t & 7;                        // 8 n-blocks of 128 cols

  const int tid = threadIdx.x, lane = tid & 63, wave = tid >> 6;
  const int quad = lane >> 4, l15 = lane & 15;
  const int m0 = mb * 128, n0 = nb * 128;
  const int wm = (wave >> 1) * 64, wn = (wave & 1) * 64;

  f32x4 acc[4][4] = {};

  for (int k0 = 0; k0 < K; k0 += 64) {
#pragma unroll
    for (int i = 0; i < 4; ++i) {
      int p0 = (wave * 4 + i) * 64;
      int p = p0 + lane;
      int m = p >> 3, cl = (p & 7) ^ (m & 7);
      async_load16(A  + (size_t)(m0 + m) * K + k0 + cl * 8, (char*)As + p0 * 16);
      async_load16(Bt + (size_t)(n0 + m) * K + k0 + cl * 8, (char*)Bs + p0 * 16);
    }
    __syncthreads();
#pragma unroll
    for (int ks = 0; ks < 2; ++ks) {
      bfrag af[4], bf[4];
#pragma unroll
      for (int i = 0; i < 4; ++i) {
        int m = wm + i * 16 + l15;
        int c = (ks * 4 + quad) ^ (m & 7);
        af[i] = *(const bfrag*)(As + m * 64 + c * 8);
        int n = wn + i * 16 + l15;
        int c2 = (ks * 4 + quad) ^ (n & 7);
        bf[i] = *(const bfrag*)(Bs + n * 64 + c2 * 8);
      }
#pragma unroll
      for (int i = 0; i < 4; ++i)
#pragma unroll
        for (int j = 0; j < 4; ++j)
          acc[i][j] = __builtin_amdgcn_mfma_f32_16x16x32_bf16(af[i], bf[j], acc[i][j], 0, 0, 0);
    }
    __syncthreads();
  }

#pragma unroll
  for (int j = 0; j < 4; ++j) {
    int col = n0 + wn + j * 16 + l15;
    float bv = bias[col];
#pragma unroll
    for (int i = 0; i < 4; ++i) {
      int row0 = m0 + wm + i * 16 + quad * 4;
#pragma unroll
      for (int r = 0; r < 4; ++r)
        Cf[(size_t)(row0 + r) * N + col] = acc[i][j][r] + bv;
    }
  }
}

// ---------------- flash attention (S^T/O^T formulation), causal, BC=128 ----
// Q/K in [B,T,H*D] bf16 (Q pre-scaled by log2e/32); VT in [B][H][64][T] bf16;
// O out [B,T,H*D] bf16.
// grid 1024: rr=id>>8, cc=id&255, g=cc>>6, bh=cc&63; t = {g,7-g,8+g,15-g}[rr]
// so each CU's 4 rounds sum to constant work; bh constant per slot (L2 reuse).
__global__ __launch_bounds__(256, 3) void flash_kernel(
    const unsigned short* __restrict__ Qh, const unsigned short* __restrict__ Kh,
    const unsigned short* __restrict__ VT, unsigned short* __restrict__ Oh)
{
  __shared__ __align__(16) short Ks[128 * 64];       // [key][c], per-row chunk-swizzled
  __shared__ __align__(16) short Vt[2][64 * 64];     // [half][d][key], chunk-swizzled
  __shared__ __align__(16) short Ps[4][32 * 72];     // per-wave P [qrow][key]

  const int tid = threadIdx.x, lane = tid & 63, wave = tid >> 6;
  const int quad = lane >> 4, l15 = lane & 15;
  const int id = blockIdx.x;
  const int rr = id >> 8, cc = id & 255, g = cc >> 6, bh = cc & 63;
  const int t = (rr == 0) ? g : (rr == 1) ? 7 - g : (rr == 2) ? 8 + g : 15 - g;
  const int b = bh >> 4, h = bh & 15;
  const int q0 = t * 128;

  const unsigned short* Qbase = Qh + (size_t)b * T_ * NDIM + h * 64;
  const unsigned short* Kbase = Kh + (size_t)b * T_ * NDIM + h * 64;
  const unsigned short* Vbase = VT + ((size_t)(b * 16 + h) * 64) * T_;   // rows d, stride T_

  const int wrow_lo = q0 + wave * 32;

  // Q fragments (B-operand rows = qrow); Q already carries log2e/32
  bfrag qfr[2][2];
#pragma unroll
  for (int j = 0; j < 2; ++j)
#pragma unroll
    for (int ks = 0; ks < 2; ++ks)
      qfr[j][ks] = *(const bfrag*)(Qbase + (size_t)(wrow_lo + j * 16 + l15) * NDIM + ks * 32 + quad * 8);

  float l_st[2] = {0.f, 0.f};
  f32x4 o_acc[2][4] = {};
  short* pw = &Ps[wave][0];

  for (int kv0 = 0; kv0 < q0 + 128; kv0 += 128) {
    // stage K [128 keys][64 c] and V^T [2][64 d][64 keys], one burst, async
#pragma unroll
    for (int i = 0; i < 4; ++i) {
      int p0 = (wave * 4 + i) * 64;
      int p = p0 + lane;
      int kr = p >> 3, kcl = (p & 7) ^ (kr & 7);
      async_load16(Kbase + (size_t)(kv0 + kr) * NDIM + kcl * 8, (char*)Ks + p0 * 16);
      int hh = p >> 9, d = (p >> 3) & 63, vcl = (p & 7) ^ (d & 7);
      async_load16(Vbase + (size_t)d * T_ + kv0 + hh * 64 + vcl * 8, (char*)Vt + p0 * 16);
    }
    __syncthreads();

#pragma unroll
    for (int hf = 0; hf < 2; ++hf) {
      const int kvh = kv0 + hf * 64;
      if (kvh > wrow_lo + 31) break;

      // S^T = K * Q^T : sv[j][i], row key=i*16+quad*4+r (local), col qrow=j*16+l15
      f32x4 sv[2][4] = {};
#pragma unroll
      for (int ks = 0; ks < 2; ++ks) {
        bfrag kf[4];
#pragma unroll
        for (int i = 0; i < 4; ++i) {
          int key = i * 16 + l15;
          int c = (ks * 4 + quad) ^ (key & 7);
          kf[i] = *(const bfrag*)(Ks + (hf * 64 + key) * 64 + c * 8);
        }
#pragma unroll
        for (int j = 0; j < 2; ++j)
#pragma unroll
          for (int i = 0; i < 4; ++i)
            sv[j][i] = __builtin_amdgcn_mfma_f32_16x16x32_bf16(kf[i], qfr[j][ks], sv[j][i], 0, 0, 0);
      }

      // p = exp2(S) (scale pre-folded into Q); causal zeroing on diagonal only
#pragma unroll
      for (int j = 0; j < 2; ++j)
#pragma unroll
        for (int i = 0; i < 4; ++i)
#pragma unroll
          for (int r = 0; r < 4; ++r)
            sv[j][i][r] = __builtin_amdgcn_exp2f(sv[j][i][r]);
      if (kvh + 63 > wrow_lo) {
#pragma unroll
        for (int j = 0; j < 2; ++j) {
          int qr = wrow_lo + j * 16 + l15;
#pragma unroll
          for (int i = 0; i < 4; ++i) {
            int keyb = kvh + i * 16 + quad * 4;
#pragma unroll
            for (int r = 0; r < 4; ++r)
              if (keyb + r > qr) sv[j][i][r] = 0.f;
          }
        }
      }

      // l partials (keys in-lane) + packed P store (v_cvt_pk_bf16_f32)
#pragma unroll
      for (int j = 0; j < 2; ++j) {
#pragma unroll
        for (int i = 0; i < 4; ++i) {
          l_st[j] += sv[j][i][0] + sv[j][i][1] + sv[j][i][2] + sv[j][i][3];
          uint2 pk;
          pk.x = cvt_pk_bf16(sv[j][i][0], sv[j][i][1]);
          pk.y = cvt_pk_bf16(sv[j][i][2], sv[j][i][3]);
          *(uint2*)(pw + (j * 16 + l15) * 72 + i * 16 + quad * 4) = pk;
        }
      }

      // O^T += V^T * P^T
#pragma unroll
      for (int ks = 0; ks < 2; ++ks) {
        bfrag vf[4], pf[2];
#pragma unroll
        for (int i2 = 0; i2 < 4; ++i2) {
          int d = i2 * 16 + l15;
          int c = (ks * 4 + quad) ^ (d & 7);
          vf[i2] = *(const bfrag*)(&Vt[hf][0] + d * 64 + c * 8);
        }
#pragma unroll
        for (int j = 0; j < 2; ++j)
          pf[j] = *(const bfrag*)(pw + (j * 16 + l15) * 72 + ks * 32 + quad * 8);
#pragma unroll
        for (int j = 0; j < 2; ++j)
#pragma unroll
          for (int i2 = 0; i2 < 4; ++i2)
            o_acc[j][i2] = __builtin_amdgcn_mfma_f32_16x16x32_bf16(vf[i2], pf[j], o_acc[j][i2], 0, 0, 0);
      }
    }
    __syncthreads();
  }

  // epilogue: reduce l over quad groups, scale, write packed b64
#pragma unroll
  for (int j = 0; j < 2; ++j) {
    float s = l_st[j];
    s += __shfl_xor(s, 16, 64);
    s += __shfl_xor(s, 32, 64);
    float inv = 1.f / s;
    int qr = q0 + wave * 32 + j * 16 + l15;
    size_t base = ((size_t)b * T_ + qr) * NDIM + h * 64;
#pragma unroll
    for (int i2 = 0; i2 < 4; ++i2) {
      uint2 pk;
      pk.x = cvt_pk_bf16(o_acc[j][i2][0] * inv, o_acc[j][i2][1] * inv);
      pk.y = cvt_pk_bf16(o_acc[j][i2][2] * inv, o_acc[j][i2][3] * inv);
      *(uint2*)(Oh + base + i2 * 16 + quad * 4) = pk;
    }
  }
}

extern "C" void kernel_launch(void* const* d_in, const int* in_sizes, int n_in,
                              void* d_out, int out_size, void* d_ws, size_t ws_size,
                              hipStream_t stream)
{
  const float* q  = (const float*)d_in[0];
  const float* k  = (const float*)d_in[1];
  const float* v  = (const float*)d_in[2];
  const float* Wq = (const float*)d_in[3];
  const float* Wk = (const float*)d_in[4];
  const float* Wv = (const float*)d_in[5];
  const float* Wo = (const float*)d_in[6];
  const float* bo = (const float*)d_in[7];
  float* out = (float*)d_out;

  char* w = (char*)d_ws;
  const size_t szBTC = (size_t)MROWS * C_ * 2;   // 16 MB
  const size_t szW   = (size_t)NDIM * C_ * 2;    // 2 MB
  unsigned short* qb   = (unsigned short*)(w);
  unsigned short* kb   = (unsigned short*)(w + szBTC);
  unsigned short* vb   = (unsigned short*)(w + 2 * szBTC);
  unsigned short* wqT  = (unsigned short*)(w + 3 * szBTC);
  unsigned short* wkT  = (unsigned short*)(w + 3 * szBTC + szW);
  unsigned short* wvT  = (unsigned short*)(w + 3 * szBTC + 2 * szW);
  unsigned short* woT  = (unsigned short*)(w + 3 * szBTC + 3 * szW);
  unsigned short* qhp  = (unsigned short*)(w + 3 * szBTC + 4 * szW);
  unsigned short* khp  = (unsigned short*)(w + 4 * szBTC + 4 * szW);
  unsigned short* vT   = (unsigned short*)(w + 5 * szBTC + 4 * szW);  // [B][H][64][T]
  unsigned short* attO = (unsigned short*)(w + 6 * szBTC + 4 * szW);

  prep_kernel<<<dim3(4096), 256, 0, stream>>>(q, k, v, qb, kb, vb,
                                              Wq, Wk, Wv, wqT, wkT, wvT, Wo, woT);

  // Q,K,V projections: 256x128-tile 2-phase GEMM, 768 blocks (3/CU resident)
  gemm_qkv<<<dim3(768), 512, 0, stream>>>(
      qb, kb, vb, wqT, wkT, wvT, qhp, khp, vT);

  flash_kernel<<<dim3(1024), 256, 0, stream>>>(qhp, khp, vT, attO);

  // output projection: 128x128-tile, 512 blocks (2/CU resident)
  gemm_o<<<dim3(512), 256, 0, stream>>>(attO, woT, out, bo);
}

// Round 9
// 295.449 us; speedup vs baseline: 1.0415x; 1.0415x over previous
//
#include <hip/hip_runtime.h>
#include <hip/hip_bf16.h>
#include <cstdint>
#include <cstddef>

#define B_  4
#define T_  2048
#define C_  1024
#define H_  16
#define D_  64
#define MROWS (B_*T_)      // 8192
#define NDIM  (H_*D_)      // 1024

typedef float  f32x4 __attribute__((ext_vector_type(4)));
typedef __bf16 bfrag __attribute__((ext_vector_type(8)));

__device__ __forceinline__ unsigned short f2bf(float f) {
  union { float f; unsigned u; } v; v.f = f;
  unsigned r = v.u + 0x7fffu + ((v.u >> 16) & 1u);
  return (unsigned short)(r >> 16);
}

__device__ __forceinline__ void async_load16(const void* g, void* l) {
  __builtin_amdgcn_global_load_lds((__attribute__((address_space(1))) void*)(void*)g,
                                   (__attribute__((address_space(3))) void*)l,
                                   16, 0, 0);
}

// pack two f32 -> 2xbf16 (RNE) in one VALU op; low16 = cvt(f0)
__device__ __forceinline__ unsigned cvt_pk_bf16(float f0, float f1) {
  unsigned r;
  asm("v_cvt_pk_bf16_f32 %0, %1, %2" : "=v"(r) : "v"(f0), "v"(f1));
  return r;
}

// ---------------- fused prep: cvt q/k/v -> bf16, transpose Wq/Wk/Wv, Wo ----
// Grid 4096: [0,3072): cvt, 8 x float4 per thread.
//            [3072,3840): wqkv transpose.  [3840,4096): wo transpose.
__global__ __launch_bounds__(256) void prep_kernel(
    const float* __restrict__ q, const float* __restrict__ k, const float* __restrict__ v,
    unsigned short* __restrict__ qb, unsigned short* __restrict__ kb, unsigned short* __restrict__ vb,
    const float* __restrict__ Wq, const float* __restrict__ Wk, const float* __restrict__ Wv,
    unsigned short* __restrict__ wqT, unsigned short* __restrict__ wkT, unsigned short* __restrict__ wvT,
    const float* __restrict__ Wo, unsigned short* __restrict__ woT)
{
  const int id = blockIdx.x, tid = threadIdx.x;
  if (id < 3072) {
    int z = id >> 10, blk = id & 1023;          // 1024 blocks per tensor
    const float* in = z == 0 ? q : z == 1 ? k : v;
    unsigned short* out = z == 0 ? qb : z == 1 ? kb : vb;
    int base = blk * 2048;                      // float4 units; 2048 f4/block
#pragma unroll
    for (int r2 = 0; r2 < 8; ++r2) {
      int i = (base + r2 * 256 + tid) * 4;
      float4 vv = *(const float4*)(in + i);
      ushort4 rr;
      rr.x = f2bf(vv.x); rr.y = f2bf(vv.y); rr.z = f2bf(vv.z); rr.w = f2bf(vv.w);
      *(ushort4*)(out + i) = rr;
    }
  } else if (id < 3840) {
    int u = id - 3072;
    int z = u >> 4, cblk = u & 15;
    int sel = z >> 4, h = z & 15;
    const float* in = (sel == 0 ? Wq : sel == 1 ? Wk : Wv) + (size_t)h * C_ * D_; // [C][D]
    unsigned short* out = (sel == 0 ? wqT : sel == 1 ? wkT : wvT) + (size_t)h * D_ * C_; // [D][C]
    __shared__ float tile[64][65];
    int c0 = cblk * 64;
    int x = tid & 63, y4 = tid >> 6;
    for (int r = y4; r < 64; r += 4)
      tile[r][x] = in[(size_t)(c0 + r) * D_ + x];
    __syncthreads();
    for (int r = y4; r < 64; r += 4)
      out[(size_t)r * C_ + c0 + x] = f2bf(tile[x][r]);
  } else {
    int u = id - 3840;
    __shared__ float tile[64][65];
    int i0 = (u >> 4) * 64, j0 = (u & 15) * 64;
    int x = tid & 63, y4 = tid >> 6;
    for (int r = y4; r < 64; r += 4)
      tile[r][x] = Wo[(size_t)(i0 + r) * C_ + j0 + x];
    __syncthreads();
    for (int r = y4; r < 64; r += 4)
      woT[(size_t)(j0 + r) * NDIM + i0 + x] = f2bf(tile[x][r]);
  }
}

// ---------------- QKV GEMM: C[M,N] = A[M,K] * Bt[N,K]^T (bf16, fp32 acc) ---
// 256x128 tile, BK=64, 512 threads (8 waves, 4Mx2N of 64x64), 48 KiB LDS,
// VGPR~60 -> 3 blocks/CU co-resident (768 blocks); 2-phase K-loop.
// z==0 -> bf16 out PRE-SCALED by log2(e)/32; z==1 -> bf16 row-major;
// z==2 -> V-transposed: (m=b*2048+t, n=h*64+d) -> out[((b*16+h)*64+d)*T_+t].
__global__ __launch_bounds__(512, 4) void gemm_qkv(
    const unsigned short* __restrict__ A0, const unsigned short* __restrict__ A1, const unsigned short* __restrict__ A2,
    const unsigned short* __restrict__ B0, const unsigned short* __restrict__ B1, const unsigned short* __restrict__ B2,
    void* C0, void* C1, void* C2)
{
  constexpr int K = C_;     // 1024
  constexpr int N = NDIM;   // 1024
  __shared__ __align__(16) short As[256 * 64];   // 32 KiB
  __shared__ __align__(16) short Bs[128 * 64];   // 16 KiB

  const int id = blockIdx.x;
  const int xcd = id & 7, s = id >> 3;
  const int z = s >> 5;
  const int t = s & 31;
  const int mb = xcd * 4 + (t >> 3);   // 32 m-blocks of 256 rows
  const int nb = t & 7;                // 8 n-blocks of 128 cols

  const unsigned short* A  = z == 0 ? A0 : z == 1 ? A1 : A2;
  const unsigned short* Bt = z == 0 ? B0 : z == 1 ? B1 : B2;
  void* Cv                 = z == 0 ? C0 : z == 1 ? C1 : C2;

  const int tid = threadIdx.x, lane = tid & 63, wave = tid >> 6;
  const int quad = lane >> 4, l15 = lane & 15;
  const int m0 = mb * 256, n0 = nb * 128;
  const int wm = (wave >> 1) * 64, wn = (wave & 1) * 64;
  const int wbase = tid & ~63;         // wave-uniform LDS chunk base

  f32x4 acc[4][4] = {};

  for (int k0 = 0; k0 < K; k0 += 64) {
#pragma unroll
    for (int i = 0; i < 4; ++i) {
      int p0 = i * 512 + wbase;
      int p = p0 + lane;
      int m = p >> 3, cl = (p & 7) ^ (m & 7);
      async_load16(A + (size_t)(m0 + m) * K + k0 + cl * 8, (char*)As + p0 * 16);
    }
#pragma unroll
    for (int i = 0; i < 2; ++i) {
      int p0 = i * 512 + wbase;
      int p = p0 + lane;
      int m = p >> 3, cl = (p & 7) ^ (m & 7);
      async_load16(Bt + (size_t)(n0 + m) * K + k0 + cl * 8, (char*)Bs + p0 * 16);
    }
    __syncthreads();
#pragma unroll
    for (int ks = 0; ks < 2; ++ks) {
      bfrag af[4], bf[4];
#pragma unroll
      for (int i = 0; i < 4; ++i) {
        int m = wm + i * 16 + l15;
        int c = (ks * 4 + quad) ^ (m & 7);
        af[i] = *(const bfrag*)(As + m * 64 + c * 8);
        int n = wn + i * 16 + l15;
        int c2 = (ks * 4 + quad) ^ (n & 7);
        bf[i] = *(const bfrag*)(Bs + n * 64 + c2 * 8);
      }
#pragma unroll
      for (int i = 0; i < 4; ++i)
#pragma unroll
        for (int j = 0; j < 4; ++j)
          acc[i][j] = __builtin_amdgcn_mfma_f32_16x16x32_bf16(af[i], bf[j], acc[i][j], 0, 0, 0);
    }
    __syncthreads();
  }

  if (z < 2) {
    const float sc = (z == 0) ? 0.045084220f : 1.0f;   // log2(e)/32 folded into Q
    unsigned short* Cb = (unsigned short*)Cv;
#pragma unroll
    for (int i = 0; i < 4; ++i) {
      int row0 = m0 + wm + i * 16 + quad * 4;
#pragma unroll
      for (int j = 0; j < 4; ++j) {
        int col = n0 + wn + j * 16 + l15;
#pragma unroll
        for (int r = 0; r < 4; ++r)
          Cb[(size_t)(row0 + r) * N + col] = f2bf(acc[i][j][r] * sc);
      }
    }
  } else {
    unsigned short* Vo = (unsigned short*)Cv;
#pragma unroll
    for (int i = 0; i < 4; ++i) {
      int m = m0 + wm + i * 16 + quad * 4;      // token index, 4 consecutive
      int bb = m >> 11, tt = m & 2047;
#pragma unroll
      for (int j = 0; j < 4; ++j) {
        int n = n0 + wn + j * 16 + l15;
        int hh = n >> 6, dd = n & 63;
        ushort4 pk;
        pk.x = f2bf(acc[i][j][0]); pk.y = f2bf(acc[i][j][1]);
        pk.z = f2bf(acc[i][j][2]); pk.w = f2bf(acc[i][j][3]);
        *(ushort4*)(Vo + (((size_t)bb * 16 + hh) * 64 + dd) * T_ + tt) = pk;
      }
    }
  }
}

// ---------------- output projection: 128x128 tile, 256 thr, 512 blocks -----
// 32 KiB LDS, VGPR~84 -> 2 blocks/CU co-resident (drain overlap).
// out = attO[8192,1024] x woT^T + bias (fp32 out).
__global__ __launch_bounds__(256) void gemm_o(
    const unsigned short* __restrict__ A, const unsigned short* __restrict__ Bt,
    float* __restrict__ Cf, const float* __restrict__ bias)
{
  constexpr int K = NDIM;   // 1024
  constexpr int N = C_;     // 1024
  __shared__ __align__(16) short As[128 * 64];
  __shared__ __align__(16) short Bs[128 * 64];

  const int id = blockIdx.x;
  const int xcd = id & 7, t = id >> 3;         // t in [0,64)
  const int mb = xcd * 8 + (t >> 3);           // 64 m-blocks of 128 rows
  const int nb = t & 7;                        // 8 n-blocks of 128 cols

  const int tid = threadIdx.x, lane = tid & 63, wave = tid >> 6;
  const int quad = lane >> 4, l15 = lane & 15;
  const int m0 = mb * 128, n0 = nb * 128;
  const int wm = (wave >> 1) * 64, wn = (wave & 1) * 64;

  f32x4 acc[4][4] = {};

  for (int k0 = 0; k0 < K; k0 += 64) {
#pragma unroll
    for (int i = 0; i < 4; ++i) {
      int p0 = (wave * 4 + i) * 64;
      int p = p0 + lane;
      int m = p >> 3, cl = (p & 7) ^ (m & 7);
      async_load16(A  + (size_t)(m0 + m) * K + k0 + cl * 8, (char*)As + p0 * 16);
      async_load16(Bt + (size_t)(n0 + m) * K + k0 + cl * 8, (char*)Bs + p0 * 16);
    }
    __syncthreads();
#pragma unroll
    for (int ks = 0; ks < 2; ++ks) {
      bfrag af[4], bf[4];
#pragma unroll
      for (int i = 0; i < 4; ++i) {
        int m = wm + i * 16 + l15;
        int c = (ks * 4 + quad) ^ (m & 7);
        af[i] = *(const bfrag*)(As + m * 64 + c * 8);
        int n = wn + i * 16 + l15;
        int c2 = (ks * 4 + quad) ^ (n & 7);
        bf[i] = *(const bfrag*)(Bs + n * 64 + c2 * 8);
      }
#pragma unroll
      for (int i = 0; i < 4; ++i)
#pragma unroll
        for (int j = 0; j < 4; ++j)
          acc[i][j] = __builtin_amdgcn_mfma_f32_16x16x32_bf16(af[i], bf[j], acc[i][j], 0, 0, 0);
    }
    __syncthreads();
  }

#pragma unroll
  for (int j = 0; j < 4; ++j) {
    int col = n0 + wn + j * 16 + l15;
    float bv = bias[col];
#pragma unroll
    for (int i = 0; i < 4; ++i) {
      int row0 = m0 + wm + i * 16 + quad * 4;
#pragma unroll
      for (int r = 0; r < 4; ++r)
        Cf[(size_t)(row0 + r) * N + col] = acc[i][j][r] + bv;
    }
  }
}

// ---------------- flash attention (S^T/O^T formulation), causal, BC=128 ----
// Q/K in [B,T,H*D] bf16 (Q pre-scaled by log2e/32); VT in [B][H][64][T] bf16;
// O out [B,T,H*D] bf16.
// Ps: [32 rows][64 keys] per wave with 16B-chunk XOR swizzle (chunk ^= row&7)
// on BOTH store and read — kills the 3.24M bank-conflict cycles the stride-72
// layout left (writes collapsed onto bank pairs via (row*36)%32 aliasing).
__global__ __launch_bounds__(256, 3) void flash_kernel(
    const unsigned short* __restrict__ Qh, const unsigned short* __restrict__ Kh,
    const unsigned short* __restrict__ VT, unsigned short* __restrict__ Oh)
{
  __shared__ __align__(16) short Ks[128 * 64];       // [key][c], chunk-swizzled
  __shared__ __align__(16) short Vt[2][64 * 64];     // [half][d][key], chunk-swizzled
  __shared__ __align__(16) short Ps[4][32 * 64];     // per-wave P, chunk-XOR swizzled

  const int tid = threadIdx.x, lane = tid & 63, wave = tid >> 6;
  const int quad = lane >> 4, l15 = lane & 15;
  const int id = blockIdx.x;
  const int rr = id >> 8, cc = id & 255, g = cc >> 6, bh = cc & 63;
  const int t = (rr == 0) ? g : (rr == 1) ? 7 - g : (rr == 2) ? 8 + g : 15 - g;
  const int b = bh >> 4, h = bh & 15;
  const int q0 = t * 128;

  const unsigned short* Qbase = Qh + (size_t)b * T_ * NDIM + h * 64;
  const unsigned short* Kbase = Kh + (size_t)b * T_ * NDIM + h * 64;
  const unsigned short* Vbase = VT + ((size_t)(b * 16 + h) * 64) * T_;   // rows d, stride T_

  const int wrow_lo = q0 + wave * 32;

  // Q fragments (B-operand rows = qrow); Q already carries log2e/32
  bfrag qfr[2][2];
#pragma unroll
  for (int j = 0; j < 2; ++j)
#pragma unroll
    for (int ks = 0; ks < 2; ++ks)
      qfr[j][ks] = *(const bfrag*)(Qbase + (size_t)(wrow_lo + j * 16 + l15) * NDIM + ks * 32 + quad * 8);

  float l_st[2] = {0.f, 0.f};
  f32x4 o_acc[2][4] = {};
  short* pw = &Ps[wave][0];

  for (int kv0 = 0; kv0 < q0 + 128; kv0 += 128) {
    // stage K [128 keys][64 c] and V^T [2][64 d][64 keys], one burst, async
#pragma unroll
    for (int i = 0; i < 4; ++i) {
      int p0 = (wave * 4 + i) * 64;
      int p = p0 + lane;
      int kr = p >> 3, kcl = (p & 7) ^ (kr & 7);
      async_load16(Kbase + (size_t)(kv0 + kr) * NDIM + kcl * 8, (char*)Ks + p0 * 16);
      int hh = p >> 9, d = (p >> 3) & 63, vcl = (p & 7) ^ (d & 7);
      async_load16(Vbase + (size_t)d * T_ + kv0 + hh * 64 + vcl * 8, (char*)Vt + p0 * 16);
    }
    __syncthreads();

#pragma unroll
    for (int hf = 0; hf < 2; ++hf) {
      const int kvh = kv0 + hf * 64;
      if (kvh > wrow_lo + 31) break;

      // S^T = K * Q^T : sv[j][i], row key=i*16+quad*4+r (local), col qrow=j*16+l15
      f32x4 sv[2][4] = {};
#pragma unroll
      for (int ks = 0; ks < 2; ++ks) {
        bfrag kf[4];
#pragma unroll
        for (int i = 0; i < 4; ++i) {
          int key = i * 16 + l15;
          int c = (ks * 4 + quad) ^ (key & 7);
          kf[i] = *(const bfrag*)(Ks + (hf * 64 + key) * 64 + c * 8);
        }
#pragma unroll
        for (int j = 0; j < 2; ++j)
#pragma unroll
          for (int i = 0; i < 4; ++i)
            sv[j][i] = __builtin_amdgcn_mfma_f32_16x16x32_bf16(kf[i], qfr[j][ks], sv[j][i], 0, 0, 0);
      }

      // p = exp2(S) (scale pre-folded into Q); causal zeroing on diagonal only
#pragma unroll
      for (int j = 0; j < 2; ++j)
#pragma unroll
        for (int i = 0; i < 4; ++i)
#pragma unroll
          for (int r = 0; r < 4; ++r)
            sv[j][i][r] = __builtin_amdgcn_exp2f(sv[j][i][r]);
      if (kvh + 63 > wrow_lo) {
#pragma unroll
        for (int j = 0; j < 2; ++j) {
          int qr = wrow_lo + j * 16 + l15;
#pragma unroll
          for (int i = 0; i < 4; ++i) {
            int keyb = kvh + i * 16 + quad * 4;
#pragma unroll
            for (int r = 0; r < 4; ++r)
              if (keyb + r > qr) sv[j][i][r] = 0.f;
          }
        }
      }

      // l partials + packed P store (cvt_pk + 16B-chunk XOR swizzle)
#pragma unroll
      for (int j = 0; j < 2; ++j) {
        int rowb = j * 16 + l15;
        short* prow = pw + rowb * 64;
        int rx = rowb & 7;
#pragma unroll
        for (int i = 0; i < 4; ++i) {
          l_st[j] += sv[j][i][0] + sv[j][i][1] + sv[j][i][2] + sv[j][i][3];
          uint2 pk;
          pk.x = cvt_pk_bf16(sv[j][i][0], sv[j][i][1]);
          pk.y = cvt_pk_bf16(sv[j][i][2], sv[j][i][3]);
          int cch = (i * 2 + (quad >> 1)) ^ rx;          // 16B chunk, swizzled
          *(uint2*)(prow + cch * 8 + (quad & 1) * 4) = pk;
        }
      }

      // O^T += V^T * P^T
#pragma unroll
      for (int ks = 0; ks < 2; ++ks) {
        bfrag vf[4], pf[2];
#pragma unroll
        for (int i2 = 0; i2 < 4; ++i2) {
          int d = i2 * 16 + l15;
          int c = (ks * 4 + quad) ^ (d & 7);
          vf[i2] = *(const bfrag*)(&Vt[hf][0] + d * 64 + c * 8);
        }
#pragma unroll
        for (int j = 0; j < 2; ++j) {
          int rowb = j * 16 + l15;
          pf[j] = *(const bfrag*)(pw + rowb * 64 + (((ks * 4 + quad) ^ (rowb & 7)) * 8));
        }
#pragma unroll
        for (int j = 0; j < 2; ++j)
#pragma unroll
          for (int i2 = 0; i2 < 4; ++i2)
            o_acc[j][i2] = __builtin_amdgcn_mfma_f32_16x16x32_bf16(vf[i2], pf[j], o_acc[j][i2], 0, 0, 0);
      }
    }
    __syncthreads();
  }

  // epilogue: reduce l over quad groups, scale, write packed b64
#pragma unroll
  for (int j = 0; j < 2; ++j) {
    float s = l_st[j];
    s += __shfl_xor(s, 16, 64);
    s += __shfl_xor(s, 32, 64);
    float inv = 1.f / s;
    int qr = q0 + wave * 32 + j * 16 + l15;
    size_t base = ((size_t)b * T_ + qr) * NDIM + h * 64;
#pragma unroll
    for (int i2 = 0; i2 < 4; ++i2) {
      uint2 pk;
      pk.x = cvt_pk_bf16(o_acc[j][i2][0] * inv, o_acc[j][i2][1] * inv);
      pk.y = cvt_pk_bf16(o_acc[j][i2][2] * inv, o_acc[j][i2][3] * inv);
      *(uint2*)(Oh + base + i2 * 16 + quad * 4) = pk;
    }
  }
}

extern "C" void kernel_launch(void* const* d_in, const int* in_sizes, int n_in,
                              void* d_out, int out_size, void* d_ws, size_t ws_size,
                              hipStream_t stream)
{
  const float* q  = (const float*)d_in[0];
  const float* k  = (const float*)d_in[1];
  const float* v  = (const float*)d_in[2];
  const float* Wq = (const float*)d_in[3];
  const float* Wk = (const float*)d_in[4];
  const float* Wv = (const float*)d_in[5];
  const float* Wo = (const float*)d_in[6];
  const float* bo = (const float*)d_in[7];
  float* out = (float*)d_out;

  char* w = (char*)d_ws;
  const size_t szBTC = (size_t)MROWS * C_ * 2;   // 16 MB
  const size_t szW   = (size_t)NDIM * C_ * 2;    // 2 MB
  unsigned short* qb   = (unsigned short*)(w);
  unsigned short* kb   = (unsigned short*)(w + szBTC);
  unsigned short* vb   = (unsigned short*)(w + 2 * szBTC);
  unsigned short* wqT  = (unsigned short*)(w + 3 * szBTC);
  unsigned short* wkT  = (unsigned short*)(w + 3 * szBTC + szW);
  unsigned short* wvT  = (unsigned short*)(w + 3 * szBTC + 2 * szW);
  unsigned short* woT  = (unsigned short*)(w + 3 * szBTC + 3 * szW);
  unsigned short* qhp  = (unsigned short*)(w + 3 * szBTC + 4 * szW);
  unsigned short* khp  = (unsigned short*)(w + 4 * szBTC + 4 * szW);
  unsigned short* vT   = (unsigned short*)(w + 5 * szBTC + 4 * szW);  // [B][H][64][T]
  unsigned short* attO = (unsigned short*)(w + 6 * szBTC + 4 * szW);

  prep_kernel<<<dim3(4096), 256, 0, stream>>>(q, k, v, qb, kb, vb,
                                              Wq, Wk, Wv, wqT, wkT, wvT, Wo, woT);

  // Q,K,V projections: 256x128-tile 2-phase GEMM, 768 blocks (3/CU resident)
  gemm_qkv<<<dim3(768), 512, 0, stream>>>(
      qb, kb, vb, wqT, wkT, wvT, qhp, khp, vT);

  flash_kernel<<<dim3(1024), 256, 0, stream>>>(qhp, khp, vT, attO);

  // output projection: 128x128-tile, 512 blocks (2/CU resident)
  gemm_o<<<dim3(512), 256, 0, stream>>>(attO, woT, out, bo);
}